// Round 1
// baseline (1264.089 us; speedup 1.0000x reference)
//
#include <hip/hip_runtime.h>

// ---------------------------------------------------------------------------
// DepTreeLSTM on MI355X.
// Forest: T=4096 binary trees, depth 5, 63 nodes/tree, N=258048, E=256, H=128.
// Per level d: A=[emb | ht0 | ht1] (K=512) x BT (640 cols) via bf16 MFMA,
// fused in-register LSTM epilogue. Leaves: K=256, 384 cols.
// ws layout: BT bf16 [640][512] at offset 0; c-state f32 [N][128] at 1MB.
// ---------------------------------------------------------------------------

typedef float f32x4 __attribute__((ext_vector_type(4)));
typedef __bf16 bf16x8 __attribute__((ext_vector_type(8)));

__device__ __forceinline__ unsigned short f2bf(float x) {
  unsigned int u = __float_as_uint(x);
  return (unsigned short)((u + 0x7fffu + ((u >> 16) & 1u)) >> 16);
}
__device__ __forceinline__ float sigf(float x) { return 1.f / (1.f + __expf(-x)); }
__device__ __forceinline__ float tanhfast(float x) {
  return 1.f - 2.f / (__expf(2.f * x) + 1.f);
}

// Build BT[col][k] bf16, col<640, k<512.
// k<256: emb rows  -> col<384: W_iou[k][col], col>=384: W_f[k][(col-384)&127] (dup for f0/f1)
// k>=256: h_iou rows -> col<384: U_iou[k-256][col], col>=384: U_f_w[k-256][col-384]
__global__ void prep_kernel(const float* __restrict__ Wi, const float* __restrict__ Ui,
                            const float* __restrict__ Wf, const float* __restrict__ Uf,
                            unsigned short* __restrict__ BT) {
  int idx = blockIdx.x * 256 + threadIdx.x;  // == col*512 + k, 640*512 total
  int col = idx >> 9;
  int k = idx & 511;
  float v;
  if (k < 256) {
    v = (col < 384) ? Wi[k * 384 + col] : Wf[k * 128 + ((col - 384) & 127)];
  } else {
    int kk = k & 255;
    v = (col < 384) ? Ui[kk * 384 + col] : Uf[kk * 256 + (col - 384)];
  }
  BT[idx] = f2bf(v);
}

// Fused level kernel. 256 threads = 4 waves, 64 GEMM rows per block.
// Wave w owns m-tile rows [16w,16w+16) and ALL column tiles (in-register epilogue).
template <bool LEAF>
__global__ __launch_bounds__(256, 2) void lvl_kernel(
    const float* __restrict__ emb, const float* __restrict__ cmask,
    const int* __restrict__ cidx, const int* __restrict__ ctype,
    const unsigned short* __restrict__ BT,
    const float* __restrict__ b_iou, const float* __restrict__ ufb,
    const float* __restrict__ bf_,
    float* __restrict__ hout, float* __restrict__ cbuf,
    int lc, int cntm1, int offs) {
  constexpr int KD = LEAF ? 256 : 512;   // K dimension
  constexpr int NCT = LEAF ? 24 : 40;    // 16-col tiles (384 or 640 cols)
  constexpr int STR = KD + 8;            // LDS row stride (bank-conflict pad)
  __shared__ unsigned short Albs[64][STR];

  const int tid = threadIdx.x;
  const int m0 = blockIdx.x * 64;

  // ---- stage emb (cols 0..255) as bf16 ----
#pragma unroll
  for (int it = 0; it < 16; ++it) {
    int f = it * 256 + tid;
    int r = f >> 6, c4 = f & 63;  // row in tile, float4 index
    int m = m0 + r;
    int g = ((m >> lc) * 63) + offs + (m & cntm1);
    const float4 v = *(const float4*)&emb[(size_t)g * 256 + c4 * 4];
    ushort4 p;
    p.x = f2bf(v.x); p.y = f2bf(v.y); p.z = f2bf(v.z); p.w = f2bf(v.w);
    *(ushort4*)&Albs[r][c4 * 4] = p;
  }

  // ---- stage ht0 (cols 256..383), ht1 (cols 384..511): gather children h ----
  if (!LEAF) {
    const int r = tid >> 2, q = tid & 3;
    int m = m0 + r;
    int g = ((m >> lc) * 63) + offs + (m & cntm1);
    const int ch0 = cidx[2 * g], ch1 = cidx[2 * g + 1];
    const int ty0 = ctype[2 * g], ty1 = ctype[2 * g + 1];
    const float c0 = cmask[2 * g], c1 = cmask[2 * g + 1];
    const float w00 = (ty0 == 0) ? c0 : 0.f, w01 = (ty1 == 0) ? c1 : 0.f;
    const float w10 = (ty0 == 1) ? c0 : 0.f, w11 = (ty1 == 1) ? c1 : 0.f;
#pragma unroll
    for (int jj = 0; jj < 8; ++jj) {
      int j = q * 32 + jj * 4;
      float4 a = *(const float4*)&hout[(size_t)ch0 * 128 + j];
      float4 b = *(const float4*)&hout[(size_t)ch1 * 128 + j];
      ushort4 p0, p1;
      p0.x = f2bf(w00 * a.x + w01 * b.x);
      p0.y = f2bf(w00 * a.y + w01 * b.y);
      p0.z = f2bf(w00 * a.z + w01 * b.z);
      p0.w = f2bf(w00 * a.w + w01 * b.w);
      p1.x = f2bf(w10 * a.x + w11 * b.x);
      p1.y = f2bf(w10 * a.y + w11 * b.y);
      p1.z = f2bf(w10 * a.z + w11 * b.z);
      p1.w = f2bf(w10 * a.w + w11 * b.w);
      *(ushort4*)&Albs[r][256 + j] = p0;
      *(ushort4*)&Albs[r][384 + j] = p1;
    }
  }
  __syncthreads();

  // ---- MFMA GEMM: acc[ct] = A_tile(16xK) @ B(Kx16) per 16-col tile ----
  const int lane = tid & 63;
  const int w = tid >> 6;
  const int cl = lane & 15;          // col within tile / A row within m-tile
  const int kq = (lane >> 4) << 3;   // k sub-offset (0,8,16,24)

  f32x4 acc[NCT];
#pragma unroll
  for (int i = 0; i < NCT; ++i) acc[i] = (f32x4){0.f, 0.f, 0.f, 0.f};

  const unsigned short* Arow = &Albs[(w << 4) + cl][0];
  for (int ks = 0; ks < KD / 32; ++ks) {
    const bf16x8 a = *(const bf16x8*)&Arow[ks * 32 + kq];
#pragma unroll
    for (int ct = 0; ct < NCT; ++ct) {
      const bf16x8 b = *(const bf16x8*)&BT[(size_t)(ct * 16 + cl) * 512 + ks * 32 + kq];
      acc[ct] = __builtin_amdgcn_mfma_f32_16x16x32_bf16(a, b, acc[ct], 0, 0, 0);
    }
  }

  // ---- in-register epilogue ----
  // D layout: col = lane&15, row = 4*(lane>>4)+reg
  const int rb = (lane >> 4) << 2;
#pragma unroll
  for (int r = 0; r < 4; ++r) {
    const int m = m0 + (w << 4) + rb + r;
    const int g = ((m >> lc) * 63) + offs + (m & cntm1);
    int ch0 = 0, ch1 = 0, ty0 = 0, ty1 = 0;
    float c0v = 0.f, c1v = 0.f;
    if (!LEAF) {
      ch0 = cidx[2 * g]; ch1 = cidx[2 * g + 1];
      ty0 = ctype[2 * g]; ty1 = ctype[2 * g + 1];
      c0v = cmask[2 * g]; c1v = cmask[2 * g + 1];
    }
#pragma unroll
    for (int ct = 0; ct < 8; ++ct) {
      const int hcol = ct * 16 + cl;
      const float iv = acc[ct][r] + b_iou[hcol];
      const float ov = acc[ct + 8][r] + b_iou[128 + hcol];
      const float uv = acc[ct + 16][r] + b_iou[256 + hcol];
      float cn;
      if (LEAF) {
        cn = sigf(iv) * tanhfast(uv);
      } else {
        const float f0 = acc[ct + 24][r] + ufb[hcol];
        const float f1 = acc[ct + 32][r] + ufb[128 + hcol];
        const float bfv = bf_[hcol];
        const float fa = (ty0 == 0) ? f0 : f1;  // f_pre[ty0]
        const float fb = (ty1 == 0) ? f0 : f1;  // f_pre[ty1]
        const float ft0 = sigf(fa + bfv);
        const float ft1 = sigf(fb + bfv);
        const float ccell = ft0 * cbuf[(size_t)ch0 * 128 + hcol] * c0v +
                            ft1 * cbuf[(size_t)ch1 * 128 + hcol] * c1v;
        cn = sigf(iv) * tanhfast(uv) + ccell;
      }
      const float hn = sigf(ov) * tanhfast(cn);
      cbuf[(size_t)g * 128 + hcol] = cn;
      hout[(size_t)g * 128 + hcol] = hn;
    }
  }
}

extern "C" void kernel_launch(void* const* d_in, const int* in_sizes, int n_in,
                              void* d_out, int out_size, void* d_ws, size_t ws_size,
                              hipStream_t stream) {
  (void)in_sizes; (void)n_in; (void)out_size; (void)ws_size;
  const float* emb   = (const float*)d_in[0];
  const float* cmask = (const float*)d_in[1];
  const float* W_iou = (const float*)d_in[2];
  const float* U_iou = (const float*)d_in[3];
  const float* b_iou = (const float*)d_in[4];
  const float* W_f   = (const float*)d_in[5];
  const float* U_f_w = (const float*)d_in[6];
  const float* U_f_b = (const float*)d_in[7];
  const float* b_f   = (const float*)d_in[8];
  const int* cidx    = (const int*)d_in[9];
  const int* ctype   = (const int*)d_in[10];
  float* hout = (float*)d_out;

  unsigned short* BT = (unsigned short*)d_ws;                 // 640*512*2 = 655360 B
  float* cbuf = (float*)((char*)d_ws + (size_t)(1 << 20));    // N*128*4 = 132 MB

  prep_kernel<<<1280, 256, 0, stream>>>(W_iou, U_iou, W_f, U_f_w, BT);

  // level 0 (leaves): M = 131072 rows, lc=5, offs=0
  lvl_kernel<true><<<2048, 256, 0, stream>>>(emb, cmask, cidx, ctype, BT, b_iou,
                                             U_f_b, b_f, hout, cbuf, 5, 31, 0);
  // levels 1..5
  static const int OFFS[6] = {0, 32, 48, 56, 60, 62};
  for (int d = 1; d <= 5; ++d) {
    const int lc = 5 - d;                 // log2(nodes per tree at level d)
    const int blocks = 64 << lc;          // M/64 = (4096<<lc)/64
    lvl_kernel<false><<<blocks, 256, 0, stream>>>(emb, cmask, cidx, ctype, BT, b_iou,
                                                  U_f_b, b_f, hout, cbuf,
                                                  lc, (1 << lc) - 1, OFFS[d]);
  }
}

// Round 2
// 398.325 us; speedup vs baseline: 3.1735x; 3.1735x over previous
//
#include <hip/hip_runtime.h>

// ---------------------------------------------------------------------------
// DepTreeLSTM on MI355X — round 2.
// Forest: T=4096 binary trees, depth 5, 63 nodes/tree, N=258048, E=256, H=128.
// Per level: A=[emb | ht0 | ht1] (K=512) x B (640 cols) via bf16 MFMA,
// fused in-register LSTM epilogue.
// Block = 512 threads (8 waves) x 128 rows. Wave w owns col-tiles
// {w, 8+w, 16+w, 24+w, 32+w} == hcol range [16w,16w+16) for i,o,u,f0,f1
// so the epilogue needs no cross-wave exchange. Each B fragment is reused
// by 8 MFMAs (8 m-tiles); block reads B exactly once (655KB).
// A staged in LDS in MFMA-fragment order (conflict-free contiguous reads).
// B pre-packed by prep kernel in fragment order (coalesced 1KB wave reads).
// ws: BTf bf16 [40][16][64][8] at 0; c-state f32 [N][128] at 1MB.
// ---------------------------------------------------------------------------

typedef float f32x4 __attribute__((ext_vector_type(4)));
typedef __bf16 bf16x8 __attribute__((ext_vector_type(8)));

__device__ __forceinline__ unsigned short f2bf(float x) {
  unsigned int u = __float_as_uint(x);
  return (unsigned short)((u + 0x7fffu + ((u >> 16) & 1u)) >> 16);
}
__device__ __forceinline__ float sigf(float x) { return 1.f / (1.f + __expf(-x)); }
__device__ __forceinline__ float tanhfast(float x) {
  return 1.f - 2.f / (__expf(2.f * x) + 1.f);
}

// Pack B into fragment order: BTf[((tile*16 + ks)*64 + lane)*8 + j]
// where lane = kq*16 + cl, col = tile*16+cl, k = ks*32 + kq*8 + j.
// col<384: W_iou/U_iou; col>=384: W_f (dup f0/f1) / U_f_w.
__global__ void prep_kernel(const float* __restrict__ Wi, const float* __restrict__ Ui,
                            const float* __restrict__ Wf, const float* __restrict__ Uf,
                            unsigned short* __restrict__ BTf) {
  int idx = blockIdx.x * 256 + threadIdx.x;  // 0 .. 40*16*64*8-1 = 327679
  int j = idx & 7;
  int lane = (idx >> 3) & 63;
  int ks = (idx >> 9) & 15;
  int tile = idx >> 13;
  int cl = lane & 15, kq = lane >> 4;
  int col = tile * 16 + cl;
  int k = ks * 32 + kq * 8 + j;
  float v;
  if (k < 256) {
    v = (col < 384) ? Wi[k * 384 + col] : Wf[k * 128 + ((col - 384) & 127)];
  } else {
    int kk = k & 255;
    v = (col < 384) ? Ui[kk * 384 + col] : Uf[kk * 256 + (col - 384)];
  }
  BTf[idx] = f2bf(v);
}

// A-LDS fragment-order address (elements): ((mt*NKS + ks)*64 + kq*16 + r)*8 + j
// for row r of m-tile mt, element k = ks*32 + kq*8 + j.
template <int NKS>
__device__ __forceinline__ int a_addr(int rblk, int k) {
  int mt = rblk >> 4, r = rblk & 15;
  int ks = k >> 5, kq = (k >> 3) & 3, j = k & 7;
  return (((mt * NKS + ks) * 64 + (kq << 4) + r) << 3) + j;
}

template <bool LEAF>
__global__ __launch_bounds__(512, 2) void lvl_kernel(
    const float* __restrict__ emb, const float* __restrict__ cmask,
    const int* __restrict__ cidx, const int* __restrict__ ctype,
    const unsigned short* __restrict__ BTf,
    const float* __restrict__ b_iou, const float* __restrict__ ufb,
    const float* __restrict__ bf_,
    float* __restrict__ hout, float* __restrict__ cbuf,
    int lc, int cntm1, int offs) {
  constexpr int KD = LEAF ? 256 : 512;
  constexpr int NKS = KD / 32;         // 8 or 16
  constexpr int NT = LEAF ? 3 : 5;     // col-tiles per wave
  __shared__ unsigned short Alds[128 * KD];

  const int tid = threadIdx.x;
  const int m0 = blockIdx.x * 128;

  // ---- stage emb (k 0..255) into fragment-order LDS as bf16 ----
#pragma unroll
  for (int it = 0; it < 16; ++it) {
    int f = it * 512 + tid;
    int rblk = f >> 6, c4 = f & 63;
    int m = m0 + rblk;
    int g = ((m >> lc) * 63) + offs + (m & cntm1);
    const float4 v = *(const float4*)&emb[(size_t)g * 256 + c4 * 4];
    ushort4 p;
    p.x = f2bf(v.x); p.y = f2bf(v.y); p.z = f2bf(v.z); p.w = f2bf(v.w);
    *(ushort4*)&Alds[a_addr<NKS>(rblk, c4 * 4)] = p;
  }

  // ---- stage ht0 (k 256..383), ht1 (k 384..511): weighted child-h gather ----
  if (!LEAF) {
    const int rblk = tid >> 2, q = tid & 3;
    int m = m0 + rblk;
    int g = ((m >> lc) * 63) + offs + (m & cntm1);
    const int ch0 = cidx[2 * g], ch1 = cidx[2 * g + 1];
    const int ty0 = ctype[2 * g], ty1 = ctype[2 * g + 1];
    const float c0 = cmask[2 * g], c1 = cmask[2 * g + 1];
    const float w00 = (ty0 == 0) ? c0 : 0.f, w01 = (ty1 == 0) ? c1 : 0.f;
    const float w10 = (ty0 == 1) ? c0 : 0.f, w11 = (ty1 == 1) ? c1 : 0.f;
#pragma unroll
    for (int jj = 0; jj < 8; ++jj) {
      int j = q * 32 + jj * 4;
      float4 a = *(const float4*)&hout[(size_t)ch0 * 128 + j];
      float4 b = *(const float4*)&hout[(size_t)ch1 * 128 + j];
      ushort4 p0, p1;
      p0.x = f2bf(w00 * a.x + w01 * b.x);
      p0.y = f2bf(w00 * a.y + w01 * b.y);
      p0.z = f2bf(w00 * a.z + w01 * b.z);
      p0.w = f2bf(w00 * a.w + w01 * b.w);
      p1.x = f2bf(w10 * a.x + w11 * b.x);
      p1.y = f2bf(w10 * a.y + w11 * b.y);
      p1.z = f2bf(w10 * a.z + w11 * b.z);
      p1.w = f2bf(w10 * a.w + w11 * b.w);
      *(ushort4*)&Alds[a_addr<NKS>(rblk, 256 + j)] = p0;
      *(ushort4*)&Alds[a_addr<NKS>(rblk, 384 + j)] = p1;
    }
  }
  __syncthreads();

  // ---- MFMA GEMM ----
  const int lane = tid & 63;
  const int w = tid >> 6;  // wave 0..7

  f32x4 acc[8][NT];
#pragma unroll
  for (int mt = 0; mt < 8; ++mt)
#pragma unroll
    for (int t = 0; t < NT; ++t) acc[mt][t] = (f32x4){0.f, 0.f, 0.f, 0.f};

  for (int ks = 0; ks < NKS; ++ks) {
    bf16x8 b[NT];
#pragma unroll
    for (int t = 0; t < NT; ++t)
      b[t] = *(const bf16x8*)&BTf[(size_t)((((t * 8 + w) * 16 + ks) * 64 + lane) << 3)];
#pragma unroll
    for (int mt = 0; mt < 8; ++mt) {
      const bf16x8 a = *(const bf16x8*)&Alds[((mt * NKS + ks) * 64 + lane) << 3];
#pragma unroll
      for (int t = 0; t < NT; ++t)
        acc[mt][t] = __builtin_amdgcn_mfma_f32_16x16x32_bf16(a, b[t], acc[mt][t], 0, 0, 0);
    }
  }

  // ---- in-register epilogue: wave w handles hcol in [16w, 16w+16) ----
  // D layout: col = lane&15, row = 4*(lane>>4)+reg
  const int cl = lane & 15;
  const int rb = (lane >> 4) << 2;
  const int hcol = w * 16 + cl;
  const float bi = b_iou[hcol];
  const float bo = b_iou[128 + hcol];
  const float bu = b_iou[256 + hcol];
  float f0b = 0.f, f1b = 0.f, bfv = 0.f;
  if (!LEAF) { f0b = ufb[hcol]; f1b = ufb[128 + hcol]; bfv = bf_[hcol]; }

#pragma unroll
  for (int mt = 0; mt < 8; ++mt) {
#pragma unroll
    for (int r = 0; r < 4; ++r) {
      const int m = m0 + (mt << 4) + rb + r;
      const int g = ((m >> lc) * 63) + offs + (m & cntm1);
      const float iv = acc[mt][0][r] + bi;
      const float ov = acc[mt][1][r] + bo;
      const float uv = acc[mt][2][r] + bu;
      float cn;
      if (LEAF) {
        cn = sigf(iv) * tanhfast(uv);
      } else {
        const int ch0 = cidx[2 * g], ch1 = cidx[2 * g + 1];
        const int ty0 = ctype[2 * g], ty1 = ctype[2 * g + 1];
        const float c0v = cmask[2 * g], c1v = cmask[2 * g + 1];
        const float f0 = acc[mt][3][r] + f0b;
        const float f1 = acc[mt][4][r] + f1b;
        const float fa = (ty0 == 0) ? f0 : f1;
        const float fb = (ty1 == 0) ? f0 : f1;
        const float ft0 = sigf(fa + bfv);
        const float ft1 = sigf(fb + bfv);
        const float ccell = ft0 * cbuf[(size_t)ch0 * 128 + hcol] * c0v +
                            ft1 * cbuf[(size_t)ch1 * 128 + hcol] * c1v;
        cn = sigf(iv) * tanhfast(uv) + ccell;
      }
      const float hn = sigf(ov) * tanhfast(cn);
      cbuf[(size_t)g * 128 + hcol] = cn;
      hout[(size_t)g * 128 + hcol] = hn;
    }
  }
}

extern "C" void kernel_launch(void* const* d_in, const int* in_sizes, int n_in,
                              void* d_out, int out_size, void* d_ws, size_t ws_size,
                              hipStream_t stream) {
  (void)in_sizes; (void)n_in; (void)out_size; (void)ws_size;
  const float* emb   = (const float*)d_in[0];
  const float* cmask = (const float*)d_in[1];
  const float* W_iou = (const float*)d_in[2];
  const float* U_iou = (const float*)d_in[3];
  const float* b_iou = (const float*)d_in[4];
  const float* W_f   = (const float*)d_in[5];
  const float* U_f_w = (const float*)d_in[6];
  const float* U_f_b = (const float*)d_in[7];
  const float* b_f   = (const float*)d_in[8];
  const int* cidx    = (const int*)d_in[9];
  const int* ctype   = (const int*)d_in[10];
  float* hout = (float*)d_out;

  unsigned short* BTf = (unsigned short*)d_ws;                // 40*16*64*8*2 = 655360 B
  float* cbuf = (float*)((char*)d_ws + (size_t)(1 << 20));    // N*128*4 = 132 MB

  prep_kernel<<<1280, 256, 0, stream>>>(W_iou, U_iou, W_f, U_f_w, BTf);

  // level 0 (leaves): M = 131072 rows
  lvl_kernel<true><<<1024, 512, 0, stream>>>(emb, cmask, cidx, ctype, BTf, b_iou,
                                             U_f_b, b_f, hout, cbuf, 5, 31, 0);
  // levels 1..5: M = 4096<<lc rows, blocks = 32<<lc
  static const int OFFS[6] = {0, 32, 48, 56, 60, 62};
  for (int d = 1; d <= 5; ++d) {
    const int lc = 5 - d;
    lvl_kernel<false><<<(32 << lc), 512, 0, stream>>>(emb, cmask, cidx, ctype, BTf,
                                                      b_iou, U_f_b, b_f, hout, cbuf,
                                                      lc, (1 << lc) - 1, OFFS[d]);
  }
}